// Round 2
// baseline (286.670 us; speedup 1.0000x reference)
//
#include <hip/hip_runtime.h>

typedef __bf16 bf16;
typedef bf16 bf16x8 __attribute__((ext_vector_type(8)));
typedef bf16 bf16x4 __attribute__((ext_vector_type(4)));
typedef bf16 bf16x2 __attribute__((ext_vector_type(2)));
typedef float f32x4 __attribute__((ext_vector_type(4)));
typedef float f32x16 __attribute__((ext_vector_type(16)));
typedef int i32x4 __attribute__((ext_vector_type(4)));

#define XSZ 4194304   // 4096*1024 elements (B*S x D)
#define WSZ 1048576   // 1024*1024
#define KDIM 1024
// 0.125 * log2(e): fold 1/sqrt(dk) AND the exp->exp2 conversion into W_q
#define QSCALE 0.1803368801111137f

// ---------- helpers ----------
__device__ __forceinline__ void async16(const bf16* g, bf16* l) {
  __builtin_amdgcn_global_load_lds(
      (const __attribute__((address_space(1))) unsigned int*)g,
      (__attribute__((address_space(3))) unsigned int*)l, 16, 0, 0);
}

__device__ __forceinline__ bf16x8 ld8(const bf16* p) {  // two aligned b64 LDS reads
  bf16x4 lo = *(const bf16x4*)p;
  bf16x4 hi = *(const bf16x4*)(p + 4);
  return __builtin_shufflevector(lo, hi, 0, 1, 2, 3, 4, 5, 6, 7);
}

__device__ __forceinline__ void st8s(bf16* p, bf16x8 v) {  // two aligned b64 LDS writes
  *(bf16x4*)p       = __builtin_shufflevector(v, v, 0, 1, 2, 3);
  *(bf16x4*)(p + 4) = __builtin_shufflevector(v, v, 4, 5, 6, 7);
}

__device__ __forceinline__ f32x4 mfma16(bf16x8 a, bf16x8 b, f32x4 c) {
  return __builtin_amdgcn_mfma_f32_16x16x32_bf16(a, b, c, 0, 0, 0);
}
__device__ __forceinline__ f32x16 mfma32(bf16x8 a, bf16x8 b, f32x16 c) {
  return __builtin_amdgcn_mfma_f32_32x32x16_bf16(a, b, c, 0, 0, 0);
}

__device__ __forceinline__ int packbf2(float lo, float hi) {
  bf16x2 t; t[0] = (bf16)lo; t[1] = (bf16)hi;
  return __builtin_bit_cast(int, t);
}

// ---------- fused fp32 -> bf16 cast for all 7 tensors (dsts contiguous in ws) ----------
__global__ __launch_bounds__(256) void cast_all(const float* __restrict__ Xq, const float* __restrict__ Xk,
                                                const float* __restrict__ Xv, const float* __restrict__ Wq,
                                                const float* __restrict__ Wk, const float* __restrict__ Wv,
                                                const float* __restrict__ Wo, bf16* __restrict__ dst) {
  size_t i = ((size_t)blockIdx.x * 256 + threadIdx.x) * 8;
  const float* src; size_t off; float scale = 1.0f;
  if (i < XSZ)                { src = Xq; off = i; }
  else if (i < 2 * (size_t)XSZ) { src = Xk; off = i - XSZ; }
  else if (i < 3 * (size_t)XSZ) { src = Xv; off = i - 2 * (size_t)XSZ; }
  else if (i < 3 * (size_t)XSZ + WSZ) { src = Wq; off = i - 3 * (size_t)XSZ; scale = QSCALE; }
  else if (i < 3 * (size_t)XSZ + 2 * (size_t)WSZ) { src = Wk; off = i - 3 * (size_t)XSZ - WSZ; }
  else if (i < 3 * (size_t)XSZ + 3 * (size_t)WSZ) { src = Wv; off = i - 3 * (size_t)XSZ - 2 * (size_t)WSZ; }
  else                        { src = Wo; off = i - 3 * (size_t)XSZ - 3 * (size_t)WSZ; }
  float4 a = *(const float4*)(src + off);
  float4 b = *(const float4*)(src + off + 4);
  bf16x8 o;
  o[0] = (bf16)(a.x * scale); o[1] = (bf16)(a.y * scale);
  o[2] = (bf16)(a.z * scale); o[3] = (bf16)(a.w * scale);
  o[4] = (bf16)(b.x * scale); o[5] = (bf16)(b.y * scale);
  o[6] = (bf16)(b.z * scale); o[7] = (bf16)(b.w * scale);
  *(bf16x8*)(dst + i) = o;
}

// ---------- m97-style NT GEMM core: C[128x128] += A[m,:] . B[n,:] ----------
__device__ __forceinline__ void gemm_nt_core(const bf16* __restrict__ A, const bf16* __restrict__ Bm,
                                             int m0, int n0, bf16* lds, f32x4 acc[4][4]) {
  const int t = threadIdx.x;
  const int lane = t & 63, wave = t >> 6;
  const int wm = wave & 1, wn = wave >> 1;
  const int quad = lane >> 4, m16 = lane & 15;
  bf16* As = lds;              // [128][32] row-major, no pad (global_load_lds constraint)
  bf16* Bs = lds + 128 * 32;
  const int c0 = t, c1 = t + 256;
  const bf16* ga0 = A + (size_t)(m0 + (c0 >> 2)) * KDIM + (c0 & 3) * 8;
  const bf16* ga1 = A + (size_t)(m0 + (c1 >> 2)) * KDIM + (c1 & 3) * 8;
  const bf16* gb0 = Bm + (size_t)(n0 + (c0 >> 2)) * KDIM + (c0 & 3) * 8;
  const bf16* gb1 = Bm + (size_t)(n0 + (c1 >> 2)) * KDIM + (c1 & 3) * 8;
  for (int kt = 0; kt < KDIM; kt += 32) {
    async16(ga0 + kt, As + c0 * 8);
    async16(ga1 + kt, As + c1 * 8);
    async16(gb0 + kt, Bs + c0 * 8);
    async16(gb1 + kt, Bs + c1 * 8);
    __syncthreads();
    bf16x8 af[4], bfv[4];
    #pragma unroll
    for (int i = 0; i < 4; i++)
      af[i] = *(const bf16x8*)(As + (wm * 64 + i * 16 + m16) * 32 + quad * 8);
    #pragma unroll
    for (int i = 0; i < 4; i++)
      bfv[i] = *(const bf16x8*)(Bs + (wn * 64 + i * 16 + m16) * 32 + quad * 8);
    #pragma unroll
    for (int mi = 0; mi < 4; mi++)
      #pragma unroll
      for (int ni = 0; ni < 4; ni++)
        acc[mi][ni] = mfma16(af[mi], bfv[ni], acc[mi][ni]);
    __syncthreads();
  }
}

// ---------- fused Q/K/V projection ----------
__global__ __launch_bounds__(256) void proj_gemm(const bf16* __restrict__ xq, const bf16* __restrict__ xk,
                                                 const bf16* __restrict__ xv, const bf16* __restrict__ wq,
                                                 const bf16* __restrict__ wk, const bf16* __restrict__ wv,
                                                 bf16* __restrict__ Qo, bf16* __restrict__ Ko,
                                                 bf16* __restrict__ Vo) {
  __shared__ bf16 lds[2 * 128 * 32];
  const int z = blockIdx.z;
  const bf16* A = (z == 0) ? xq : (z == 1) ? xk : xv;
  const bf16* W = (z == 0) ? wq : (z == 1) ? wk : wv;
  bf16* C = (z == 0) ? Qo : (z == 1) ? Ko : Vo;
  f32x4 acc[4][4];
  #pragma unroll
  for (int i = 0; i < 4; i++)
    #pragma unroll
    for (int j = 0; j < 4; j++) acc[i][j] = (f32x4){0.f, 0.f, 0.f, 0.f};
  gemm_nt_core(A, W, blockIdx.y * 128, blockIdx.x * 128, lds, acc);
  const int lane = threadIdx.x & 63, wave = threadIdx.x >> 6;
  const int wm = wave & 1, wn = wave >> 1, quad = lane >> 4, m16 = lane & 15;
  const int row0 = blockIdx.y * 128 + wm * 64;
  const int col0 = blockIdx.x * 128 + wn * 64;
  #pragma unroll
  for (int mi = 0; mi < 4; mi++)
    #pragma unroll
    for (int ni = 0; ni < 4; ni++)
      #pragma unroll
      for (int r = 0; r < 4; r++) {
        int row = row0 + mi * 16 + quad * 4 + r;
        int col = col0 + ni * 16 + m16;
        C[(size_t)row * 1024 + col] = (bf16)acc[mi][ni][r];
      }
}

// ---------- output projection: fp32 out + bias ----------
__global__ __launch_bounds__(256) void out_gemm(const bf16* __restrict__ Hm, const bf16* __restrict__ wo,
                                                const float* __restrict__ bias, float* __restrict__ out) {
  __shared__ bf16 lds[2 * 128 * 32];
  f32x4 acc[4][4];
  #pragma unroll
  for (int i = 0; i < 4; i++)
    #pragma unroll
    for (int j = 0; j < 4; j++) acc[i][j] = (f32x4){0.f, 0.f, 0.f, 0.f};
  gemm_nt_core(Hm, wo, blockIdx.y * 128, blockIdx.x * 128, lds, acc);
  const int lane = threadIdx.x & 63, wave = threadIdx.x >> 6;
  const int wm = wave & 1, wn = wave >> 1, quad = lane >> 4, m16 = lane & 15;
  const int row0 = blockIdx.y * 128 + wm * 64;
  const int col0 = blockIdx.x * 128 + wn * 64;
  float bv[4];
  #pragma unroll
  for (int ni = 0; ni < 4; ni++) bv[ni] = bias[col0 + ni * 16 + m16];
  #pragma unroll
  for (int mi = 0; mi < 4; mi++)
    #pragma unroll
    for (int ni = 0; ni < 4; ni++)
      #pragma unroll
      for (int r = 0; r < 4; r++) {
        int row = row0 + mi * 16 + quad * 4 + r;
        int col = col0 + ni * 16 + m16;
        out[(size_t)row * 1024 + col] = acc[mi][ni][r] + bv[ni];
      }
}

// ---------- V transpose per head-chunk: V[2048][64] -> Vt[64][2048] ----------
__global__ __launch_bounds__(256) void transpose_v(const bf16* __restrict__ V, bf16* __restrict__ Vt) {
  __shared__ bf16 T[64 * 65];
  const int t = threadIdx.x;
  const bf16* src = V + (size_t)blockIdx.y * (2048 * 64) + (size_t)blockIdx.x * 64 * 64;
  bf16* dst = Vt + (size_t)blockIdx.y * (2048 * 64) + (size_t)blockIdx.x * 64;
  #pragma unroll
  for (int j = 0; j < 2; j++) {
    int c = t + j * 256;
    int row = c >> 3, col8 = (c & 7) * 8;
    bf16x8 v = *(const bf16x8*)(src + row * 64 + col8);
    #pragma unroll
    for (int i = 0; i < 8; i++) T[row * 65 + col8 + i] = v[i];
  }
  __syncthreads();
  #pragma unroll
  for (int j = 0; j < 2; j++) {
    int c = t + j * 256;
    int d = c >> 3, k8 = (c & 7) * 8;
    bf16x8 o;
    #pragma unroll
    for (int i = 0; i < 8; i++) o[i] = T[(k8 + i) * 65 + d];
    *(bf16x8*)(dst + (size_t)d * 2048 + k8) = o;
  }
}

// ---------- flash attention, S^T formulation with 32x32x16 MFMA ----------
// S^T = K.Q^T : A=K (m=key), B=Q^T (n=q). C-layout: col=q=lane&31,
// row=key=(reg&3)+8*(reg>>2)+4*(lane>>5). Softmax stats are per-lane scalars.
// P^T converts to the PV B-operand (k=(lane>>5)*8+j, n=lane&31) with 2 packed
// shfl_xor(32) + selects per 16-key chunk -> NO LDS round-trip for P.
// O^T = V^T.P^T accumulated in C-layout; epilogue stores packed b64.
// Wave w owns q-cols [128*bx + 32w, +32). K-tile = 128 keys.
#define KS 68    // K LDS row stride (elems): 34 dwords == 2 mod 32 -> conflict-free b64
#define VS 132   // V^T LDS row stride: 66 dwords == 2 mod 32
__global__ __launch_bounds__(256, 2) void attn_kernel(const bf16* __restrict__ Qg,
                                                      const bf16* __restrict__ Kg,
                                                      const bf16* __restrict__ Vtg,
                                                      bf16* __restrict__ Og) {
  __shared__ bf16 smem[128 * KS + 64 * VS];  // 34304 B
  bf16* Ks = smem;
  bf16* Vs = smem + 128 * KS;
  const int t = threadIdx.x;
  const int lane = t & 63, w = t >> 6;
  const int l31 = lane & 31, h = lane >> 5;
  const size_t base = (size_t)blockIdx.y * (2048 * 64);
  const bf16* Kp = Kg + base;
  const bf16* Vp = Vtg + base;
  const int q = blockIdx.x * 128 + w * 32 + l31;   // this lane's q-column

  // Q fragments (B-operand: n=l31, k=16kc+8h+j) held in registers all loop
  bf16x8 qf[4];
  #pragma unroll
  for (int kc = 0; kc < 4; kc++)
    qf[kc] = *(const bf16x8*)(Qg + base + (size_t)q * 64 + 16 * kc + 8 * h);

  f32x16 oacc[2];
  #pragma unroll
  for (int mt = 0; mt < 2; mt++)
    #pragma unroll
    for (int i = 0; i < 16; i++) oacc[mt][i] = 0.f;
  float mrow = -INFINITY, lrow = 0.f;   // per-lane scalars (log2 units)

  for (int kt = 0; kt < 2048; kt += 128) {
    // stage K tile (128x64) and V^T tile (64x128)
    #pragma unroll
    for (int j = 0; j < 4; j++) {
      int c = t + j * 256;
      int row = c >> 3, col8 = (c & 7) * 8;
      st8s(Ks + row * KS + col8, *(const bf16x8*)(Kp + (size_t)(kt + row) * 64 + col8));
    }
    #pragma unroll
    for (int j = 0; j < 4; j++) {
      int c = t + j * 256;
      int d = c >> 4, col8 = (c & 15) * 8;
      st8s(Vs + d * VS + col8, *(const bf16x8*)(Vp + (size_t)d * 2048 + kt + col8));
    }
    __syncthreads();

    // S^T = K . Q^T (keys local 0..127 in 4 m-tiles)
    f32x16 sacc[4];
    #pragma unroll
    for (int mt = 0; mt < 4; mt++)
      #pragma unroll
      for (int i = 0; i < 16; i++) sacc[mt][i] = 0.f;
    #pragma unroll
    for (int mt = 0; mt < 4; mt++)
      #pragma unroll
      for (int kc = 0; kc < 4; kc++) {
        bf16x8 kf = ld8(Ks + (32 * mt + l31) * KS + 16 * kc + 8 * h);
        sacc[mt] = mfma32(kf, qf[kc], sacc[mt]);
      }

    // online softmax (per-lane: 64 of the 128 keys; halves merged via xor-32)
    float mx = sacc[0][0];
    #pragma unroll
    for (int mt = 0; mt < 4; mt++)
      #pragma unroll
      for (int i = 0; i < 16; i++) mx = fmaxf(mx, sacc[mt][i]);
    mx = fmaxf(mx, __shfl_xor(mx, 32, 64));
    float mnew = fmaxf(mrow, mx);
    float a = exp2f(mrow - mnew);
    float sum = 0.f;
    int pd[4][8];   // P^T as packed bf16 pairs (regs 2p, 2p+1)
    #pragma unroll
    for (int mt = 0; mt < 4; mt++)
      #pragma unroll
      for (int p = 0; p < 8; p++) {
        float p0 = exp2f(sacc[mt][2 * p] - mnew);
        float p1 = exp2f(sacc[mt][2 * p + 1] - mnew);
        sum += p0 + p1;
        pd[mt][p] = packbf2(p0, p1);
      }
    sum += __shfl_xor(sum, 32, 64);
    lrow = lrow * a + sum;
    mrow = mnew;
    #pragma unroll
    for (int mt = 0; mt < 2; mt++)
      #pragma unroll
      for (int i = 0; i < 16; i++) oacc[mt][i] *= a;

    // O^T += V^T . P^T
    #pragma unroll
    for (int kc = 0; kc < 8; kc++) {
      const int mts = kc >> 1, c1 = kc & 1;
      const int rro = 2 * c1 + h;        // own reg-group
      const int rrp = 2 * c1 + 1 - h;    // what the partner half needs from us
      int s0 = __shfl_xor(pd[mts][2 * rrp], 32, 64);
      int s1 = __shfl_xor(pd[mts][2 * rrp + 1], 32, 64);
      int o0 = pd[mts][2 * rro], o1 = pd[mts][2 * rro + 1];
      i32x4 w4;
      w4.x = h ? s0 : o0;   // j0..1 (h_src=0)
      w4.y = h ? s1 : o1;   // j2..3
      w4.z = h ? o0 : s0;   // j4..5 (h_src=1)
      w4.w = h ? o1 : s1;   // j6..7
      bf16x8 pfrag = __builtin_bit_cast(bf16x8, w4);
      #pragma unroll
      for (int mtd = 0; mtd < 2; mtd++) {
        bf16x8 vf = ld8(Vs + (32 * mtd + l31) * VS + 16 * kc + 8 * h);
        oacc[mtd] = mfma32(vf, pfrag, oacc[mtd]);
      }
    }
    __syncthreads();   // Ks/Vs reads done before next stage
  }

  // epilogue: O[q][d] = O^T acc / l, packed 4-wide stores
  float inv = 1.f / lrow;
  #pragma unroll
  for (int mt = 0; mt < 2; mt++)
    #pragma unroll
    for (int r2 = 0; r2 < 4; r2++) {
      bf16x4 ov;
      #pragma unroll
      for (int i = 0; i < 4; i++) ov[i] = (bf16)(oacc[mt][4 * r2 + i] * inv);
      *(bf16x4*)(Og + base + (size_t)q * 64 + 32 * mt + 8 * r2 + 4 * h) = ov;
    }
}

// ---------- launch ----------
extern "C" void kernel_launch(void* const* d_in, const int* in_sizes, int n_in,
                              void* d_out, int out_size, void* d_ws, size_t ws_size,
                              hipStream_t stream) {
  const float* Xq = (const float*)d_in[0];
  const float* Xk = (const float*)d_in[1];
  const float* Xv = (const float*)d_in[2];
  const float* Wq = (const float*)d_in[3];
  const float* Wk = (const float*)d_in[4];
  const float* Wv = (const float*)d_in[5];
  const float* Wo = (const float*)d_in[6];
  const float* bo = (const float*)d_in[7];

  bf16* ws = (bf16*)d_ws;
  bf16* xq = ws;                 // casts write [xq xk xv wq wk wv wo] contiguously
  bf16* xk = ws + XSZ;
  bf16* xv = ws + 2 * (size_t)XSZ;
  bf16* wq = ws + 3 * (size_t)XSZ;
  bf16* wk = wq + WSZ;
  bf16* wv = wk + WSZ;
  bf16* wo = wv + WSZ;
  bf16* q  = wo + WSZ;
  bf16* k  = q + XSZ;
  bf16* v  = k + XSZ;
  bf16* vt = xv;                 // alias: X_v dead after projection
  bf16* h  = xq;                 // alias: X_q dead after projection

  cast_all<<<8192, 256, 0, stream>>>(Xq, Xk, Xv, Wq, Wk, Wv, Wo, ws);
  proj_gemm<<<dim3(8, 32, 3), 256, 0, stream>>>(xq, xk, xv, wq, wk, wv, q, k, v);
  transpose_v<<<dim3(32, 32), 256, 0, stream>>>(v, vt);
  attn_kernel<<<dim3(16, 32), 256, 0, stream>>>(q, k, vt, h);
  out_gemm<<<dim3(8, 32), 256, 0, stream>>>(h, wo, bo, (float*)d_out);
}